// Round 8
// baseline (410.554 us; speedup 1.0000x reference)
//
#include <hip/hip_runtime.h>
#include <hip/hip_bf16.h>
#include <math.h>

#define TWO_PI_D 6.283185307179586476925286766559
#define TWO_PI_F 6.28318530718f

typedef short bf16x8 __attribute__((ext_vector_type(8)));
typedef float f32x4 __attribute__((ext_vector_type(4)));

// ---------------------------------------------------------------------------
// Harmonic basis, bf16, TRANSPOSED + padded: Ct[n][k], n<1024 (1022 valid), k<512
// ---------------------------------------------------------------------------
__global__ __launch_bounds__(256) void basis_h_bf16_t(__hip_bfloat16* __restrict__ Ct)
{
    const int n = blockIdx.x;            // 0..1023
    for (int k = threadIdx.x; k < 512; k += 256) {
        float v = 0.0f;
        if (n < 1022) {
            float hann = 0.5f * (1.0f - cosf(TWO_PI_F * (float)n / 1022.0f));
            float w = hann * (1.0f / 1022.0f);
            if (k == 0) v = w;
            else if (k == 511) v = (n & 1) ? w : -w;
            else {
                int m = (k * n) % 1022;
                float c = cosf(TWO_PI_F * (float)m / 1022.0f);
                v = 2.0f * w * ((k & 1) ? -c : c);
            }
        }
        Ct[(size_t)n * 512 + k] = __float2bfloat16(v);
    }
}

// noise basis, fp32: C[k][n], k<80, n<158
template<int NMAG, int NIR>
__global__ __launch_bounds__(256) void basis_kernel(float* __restrict__ C)
{
    const int k = blockIdx.x;
    for (int n = threadIdx.x; n < NIR; n += blockDim.x) {
        double hann = 0.5 * (1.0 - cos(TWO_PI_D * (double)n / (double)NIR));
        double w = hann / (double)NIR;
        double v;
        if (k == 0) v = w;
        else if (k == NMAG - 1) v = (n & 1) ? w : -w;
        else {
            long m = ((long)k * (long)n) % NIR;
            double c = cos(TWO_PI_D * (double)m / (double)NIR);
            v = 2.0 * w * ((k & 1) ? -c : c);
        }
        C[(size_t)k * NIR + n] = (float)v;
    }
}

// ---------------------------------------------------------------------------
// fp32 tiled GEMM 64x64x16 — precision path (MLP hidden layers + noise IR).
// ---------------------------------------------------------------------------
__device__ inline float gelu_f(float x) {
    float x3 = x * x * x;
    float t = tanhf(0.7978845608028654f * (x + 0.044715f * x3));
    return 0.5f * x * (1.0f + t);
}

template<int MODE>
__global__ __launch_bounds__(256) void gemm_kernel(
    const float* __restrict__ A, const float* __restrict__ Bm,
    const float* __restrict__ bias, const float* __restrict__ resid,
    float* __restrict__ C, __hip_bfloat16* __restrict__ Cb, int M, int N, int K)
{
    __shared__ float As[16][68];
    __shared__ float Bs[16][68];
    const int tid = threadIdx.x;
    const int tx = tid & 15, ty = tid >> 4;
    const int m0 = blockIdx.x * 64;
    const int n0 = blockIdx.y * 64;
    const int ar  = tid >> 2;
    const int ac4 = (tid & 3) << 2;
    const int bk  = tid >> 4;
    const int bn4 = (tid & 15) << 2;
    float acc[4][4] = {};
    for (int k0 = 0; k0 < K; k0 += 16) {
        float4 av = *(const float4*)(A + (size_t)(m0 + ar) * K + k0 + ac4);
        As[ac4 + 0][ar] = av.x;
        As[ac4 + 1][ar] = av.y;
        As[ac4 + 2][ar] = av.z;
        As[ac4 + 3][ar] = av.w;
        const float* Bp = Bm + (size_t)(k0 + bk) * N + n0 + bn4;
        #pragma unroll
        for (int i = 0; i < 4; i++)
            Bs[bk][bn4 + i] = (n0 + bn4 + i < N) ? Bp[i] : 0.0f;
        __syncthreads();
        #pragma unroll
        for (int kk = 0; kk < 16; kk++) {
            float4 a4 = *(const float4*)&As[kk][ty << 2];
            float4 b4 = *(const float4*)&Bs[kk][tx << 2];
            float a[4] = {a4.x, a4.y, a4.z, a4.w};
            float b[4] = {b4.x, b4.y, b4.z, b4.w};
            #pragma unroll
            for (int i = 0; i < 4; i++)
                #pragma unroll
                for (int j = 0; j < 4; j++)
                    acc[i][j] = fmaf(a[i], b[j], acc[i][j]);
        }
        __syncthreads();
    }
    #pragma unroll
    for (int i = 0; i < 4; i++) {
        int m = m0 + (ty << 2) + i;
        #pragma unroll
        for (int j = 0; j < 4; j++) {
            int n = n0 + (tx << 2) + j;
            if (n < N) {
                float v = acc[i][j];
                if (bias) v += bias[n];
                if (MODE == 0) v = tanhf(v);
                else if (MODE == 1) v = resid[(size_t)m * N + n] + gelu_f(v);
                C[(size_t)m * N + n] = v;
                if (MODE == 1 && Cb) Cb[(size_t)m * N + n] = __float2bfloat16(v);
            }
        }
    }
}

// ---------------------------------------------------------------------------
// bf16 MFMA GEMM: A [M][K] bf16, Bt [NPAD][K] bf16, C [M][NSTRIDE] fp32
// ---------------------------------------------------------------------------
template<int K, int NSTRIDE>
__global__ __launch_bounds__(256) void mfma_gemm(
    const unsigned short* __restrict__ A, const unsigned short* __restrict__ Bt,
    float* __restrict__ C, int M)
{
    __shared__ __align__(16) unsigned short As[128][72];
    __shared__ __align__(16) unsigned short Bs[128][72];
    const int tid = threadIdx.x;
    const int m0 = blockIdx.x * 128;
    const int n0 = blockIdx.y * 128;
    const int wid = tid >> 6;
    const int lane = tid & 63;
    const int wm = (wid >> 1) << 6;
    const int wn = (wid & 1) << 6;

    f32x4 acc[4][4];
    #pragma unroll
    for (int i = 0; i < 4; i++)
        #pragma unroll
        for (int j = 0; j < 4; j++)
            acc[i][j] = (f32x4){0.f, 0.f, 0.f, 0.f};

    for (int k0 = 0; k0 < K; k0 += 64) {
        #pragma unroll
        for (int s = 0; s < 4; s++) {
            int g = tid + (s << 8);
            int row = g >> 3;
            int kc = (g & 7) << 3;
            int ra = m0 + row; if (ra > M - 1) ra = M - 1;
            *(uint4*)&As[row][kc] = *(const uint4*)&A[(size_t)ra * K + k0 + kc];
            *(uint4*)&Bs[row][kc] = *(const uint4*)&Bt[(size_t)(n0 + row) * K + k0 + kc];
        }
        __syncthreads();
        #pragma unroll
        for (int kk = 0; kk < 64; kk += 32) {
            bf16x8 av[4], bv[4];
            const int koff = kk + ((lane >> 4) << 3);
            #pragma unroll
            for (int mt = 0; mt < 4; mt++)
                av[mt] = *(const bf16x8*)&As[wm + (mt << 4) + (lane & 15)][koff];
            #pragma unroll
            for (int nt = 0; nt < 4; nt++)
                bv[nt] = *(const bf16x8*)&Bs[wn + (nt << 4) + (lane & 15)][koff];
            #pragma unroll
            for (int mt = 0; mt < 4; mt++)
                #pragma unroll
                for (int nt = 0; nt < 4; nt++)
                    acc[mt][nt] = __builtin_amdgcn_mfma_f32_16x16x32_bf16(
                        av[mt], bv[nt], acc[mt][nt], 0, 0, 0);
        }
        __syncthreads();
    }
    const int cr0 = m0 + wm + ((lane >> 4) << 2);
    const int cc0 = n0 + wn + (lane & 15);
    #pragma unroll
    for (int mt = 0; mt < 4; mt++)
        #pragma unroll
        for (int nt = 0; nt < 4; nt++)
            #pragma unroll
            for (int j = 0; j < 4; j++) {
                int r = cr0 + (mt << 4) + j;
                if (r < M) C[(size_t)r * NSTRIDE + cc0 + (nt << 4)] = acc[mt][nt][j];
            }
}

// ---------------------------------------------------------------------------
__global__ __launch_bounds__(256) void convert_wout(
    const float* __restrict__ W, __hip_bfloat16* __restrict__ WTb)
{
    const int n = blockIdx.x;           // 0..639
    const int k = threadIdx.x;          // 0..255
    float v = (n < 593) ? W[(size_t)k * 593 + n] : 0.0f;
    WTb[(size_t)n * 256 + k] = __float2bfloat16(v);
}

// exact-fp32 f0 logit + fused precise f0 transform
__global__ __launch_bounds__(256) void f0_gemv(
    const float* __restrict__ h3, const float* __restrict__ Wout,
    const float* __restrict__ b_out, float* __restrict__ f0w, float* __restrict__ f0out)
{
    const int row = blockIdx.x * 4 + (threadIdx.x >> 6);
    const int lane = threadIdx.x & 63;
    const float* a = h3 + (size_t)row * 256;
    float s = 0.0f;
    #pragma unroll
    for (int q = 0; q < 4; q++) {
        int k = lane + (q << 6);
        s = fmaf(a[k], Wout[(size_t)k * 593], s);
    }
    #pragma unroll
    for (int off = 32; off; off >>= 1) s += __shfl_down(s, off, 64);
    if (lane == 0) {
        float lg = s + b_out[0];
        float sg = 1.0f / (1.0f + expf(-lg));
        float f0 = 80.0f * powf(12.5f, sg);
        if (f0 < 80.0f) f0 = 0.0f;
        f0w[row] = f0;
        f0out[row] = f0;
    }
}

// ---------------------------------------------------------------------------
// SP/NP from O[8000][640] cols 1..592 (+bias), fast-math exp_sigmoid
// ---------------------------------------------------------------------------
__global__ __launch_bounds__(256) void transform2_kernel(
    const float* __restrict__ O, const float* __restrict__ b_out,
    __hip_bfloat16* __restrict__ SPb, float* __restrict__ NP)
{
    int idx = blockIdx.x * 256 + threadIdx.x;
    if (idx >= 8000 * 592) return;
    int row = idx / 592;
    int c = idx - row * 592 + 1;
    float v = O[(size_t)row * 640 + c] + b_out[c];
    float s = 1.0f / (1.0f + __expf(-v));
    float p = 2.0f * __powf(s, 2.3025851f) + 1e-7f;
    if (c < 513) SPb[(size_t)row * 512 + (c - 1)] = __float2bfloat16(p);
    else         NP[(size_t)row * 80 + (c - 513)] = p;
}

// ---------------------------------------------------------------------------
// Parallel fp64 frame-level pitch scan
// ---------------------------------------------------------------------------
__device__ inline double shfl_up_d(double x, int off) {
    long long l = __double_as_longlong(x);
    int lo = (int)(l & 0xffffffffLL);
    int hi = (int)(l >> 32);
    lo = __shfl_up(lo, off, 64);
    hi = __shfl_up(hi, off, 64);
    return __longlong_as_double(((long long)hi << 32) | (unsigned int)lo);
}

__global__ __launch_bounds__(256) void scan_par_kernel(
    const float* __restrict__ f0w, const float* __restrict__ iphase,
    double* __restrict__ base, float* __restrict__ fph)
{
    __shared__ double wsum[4];
    const int b = blockIdx.x;
    const int tid = threadIdx.x;
    const int lane = tid & 63;
    const float* f0 = f0w + b * 1000;
    double s[4];
    double loc = 0.0;
    #pragma unroll
    for (int q = 0; q < 4; q++) {
        int f = tid * 4 + q;
        s[q] = loc;
        if (f < 1000) {
            double c  = (double)f0[f];
            double nx = (double)f0[(f < 999) ? (f + 1) : 999];
            loc += 120.5 * c + 119.5 * nx;
        }
    }
    double v = loc;
    #pragma unroll
    for (int off = 1; off < 64; off <<= 1) {
        double o = shfl_up_d(v, off);
        if (lane >= off) v += o;
    }
    if (lane == 63) wsum[tid >> 6] = v;
    __syncthreads();
    double wpre = 0.0;
    const int w = tid >> 6;
    for (int i = 0; i < w; i++) wpre += wsum[i];
    const double excl = wpre + v - loc;
    #pragma unroll
    for (int q = 0; q < 4; q++) {
        int f = tid * 4 + q;
        if (f < 1000) base[b * 1000 + f] = excl + s[q];
    }
    if (tid == 255) {
        double total = excl + loc;
        double u  = total * (1.0 / 24000.0);
        double ph = TWO_PI_D * u + (double)iphase[b];
        fph[b] = (float)fmod(ph, TWO_PI_D);
    }
}

// ---------------------------------------------------------------------------
// Sawtooth (fp64 phase) + threefry2x32 noise (bit-exact)
// ---------------------------------------------------------------------------
__device__ inline unsigned rotl32(unsigned x, int d) { return (x << d) | (x >> (32 - d)); }

__global__ __launch_bounds__(256) void saw_noise_kernel(
    const float* __restrict__ f0w, const double* __restrict__ base,
    const float* __restrict__ iphase, float* __restrict__ saw, float* __restrict__ nz)
{
    int idx = blockIdx.x * 256 + threadIdx.x;
    if (idx >= 8 * 240000) return;
    int b = idx / 240000;
    int t = idx - b * 240000;
    int f = t / 240;
    int r = t - f * 240;
    double c  = (double)f0w[b * 1000 + f];
    double nx = (double)f0w[b * 1000 + ((f < 999) ? (f + 1) : 999)];
    double rr = (double)r;
    double Bc = rr * (rr + 1.0) * (1.0 / 480.0);
    double Ac = (rr + 1.0) - Bc;
    double cum = base[b * 1000 + f] + Ac * c + Bc * nx;
    double u  = cum * (1.0 / 24000.0) + (double)iphase[b] * (1.0 / TWO_PI_D);
    double fr = u - floor(u);
    saw[idx] = (float)(2.0 * fr - 1.0);

    const unsigned n2 = 960000u;
    unsigned mi = (unsigned)idx;
    unsigned i0 = (mi < n2) ? mi : (mi - n2);
    unsigned x0 = i0, x1 = i0 + n2;
    const unsigned ks0 = 0u, ks1 = 123u, ks2 = 0x1BD11BDAu ^ 0u ^ 123u;
    x0 += ks0; x1 += ks1;
#define TF_R(rot) { x0 += x1; x1 = rotl32(x1, rot); x1 ^= x0; }
    TF_R(13) TF_R(15) TF_R(26) TF_R(6)
    x0 += ks1; x1 += ks2 + 1u;
    TF_R(17) TF_R(29) TF_R(16) TF_R(24)
    x0 += ks2; x1 += ks0 + 2u;
    TF_R(13) TF_R(15) TF_R(26) TF_R(6)
    x0 += ks0; x1 += ks1 + 3u;
    TF_R(17) TF_R(29) TF_R(16) TF_R(24)
    x0 += ks1; x1 += ks2 + 4u;
    TF_R(13) TF_R(15) TF_R(26) TF_R(6)
    x0 += ks2; x1 += ks0 + 5u;
#undef TF_R
    unsigned bits = (mi < n2) ? x0 : x1;
    float uf = __uint_as_float((bits >> 9) | 0x3f800000u) - 1.0f;
    nz[idx] = uf * 2.0f - 1.0f;
}

// ---------------------------------------------------------------------------
// Per-frame conv, harmonic: one frame per 320-thread block, 4 outputs/thread.
// Per-lane w-read is stride-1-chunk (64 consecutive chunks per wave = LDS
// floor, zero excess conflicts); u-read is full-wave uniform broadcast.
// ---------------------------------------------------------------------------
#define CONV_GROUP(u4) \
    a0 = fmaf(u4.x, Whi.x, a0); a1 = fmaf(u4.x, Whi.y, a1); a2 = fmaf(u4.x, Whi.z, a2); a3 = fmaf(u4.x, Whi.w, a3); \
    a0 = fmaf(u4.y, Wlo.w, a0); a1 = fmaf(u4.y, Whi.x, a1); a2 = fmaf(u4.y, Whi.y, a2); a3 = fmaf(u4.y, Whi.z, a3); \
    a0 = fmaf(u4.z, Wlo.z, a0); a1 = fmaf(u4.z, Wlo.w, a1); a2 = fmaf(u4.z, Whi.x, a2); a3 = fmaf(u4.z, Whi.y, a3); \
    a0 = fmaf(u4.w, Wlo.y, a0); a1 = fmaf(u4.w, Wlo.z, a1); a2 = fmaf(u4.w, Wlo.w, a2); a3 = fmaf(u4.w, Whi.x, a3);

__global__ __launch_bounds__(320) void frameconv_h(
    const float* __restrict__ audio, const float* __restrict__ IR,
    float* __restrict__ Y)
{
    __shared__ __align__(16) float u_s[240];
    __shared__ __align__(16) float w_s[1520];
    const int f = blockIdx.x;
    const int b = blockIdx.y;
    const int tid = threadIdx.x;
    for (int i = tid; i < 240; i += 320) {
        u_s[i] = audio[(size_t)b * 240000 + (size_t)f * 240 + i];
        w_s[i] = 0.0f;
    }
    for (int i = tid; i < 258; i += 320) w_s[1262 + i] = 0.0f;
    const float* irow = IR + ((size_t)b * 1000 + f) * 1024;
    for (int i = tid; i < 1022; i += 320) w_s[240 + i] = irow[i];
    __syncthreads();

    const int j0 = tid << 2;
    int base = 240 + j0 - 4;
    float4 Wlo = *(const float4*)&w_s[base];
    float4 Whi = *(const float4*)&w_s[base + 4];
    float a0 = 0.f, a1 = 0.f, a2 = 0.f, a3 = 0.f;
    #pragma unroll 4
    for (int t = 0; t < 236; t += 4) {
        float4 u4 = *(const float4*)&u_s[t];
        CONV_GROUP(u4)
        Whi = Wlo;
        base -= 4;
        Wlo = *(const float4*)&w_s[base];
    }
    {
        float4 u4 = *(const float4*)&u_s[236];
        CONV_GROUP(u4)
    }
    float4 r; r.x = a0; r.y = a1; r.z = a2; r.w = a3;
    *(float4*)&Y[((size_t)b * 1000 + f) * 1280 + j0] = r;
}

// ---------------------------------------------------------------------------
// Per-frame conv, noise: iterate IR, window over audio.
// ---------------------------------------------------------------------------
__global__ __launch_bounds__(128) void frameconv_n(
    const float* __restrict__ audio, const float* __restrict__ IR,
    float* __restrict__ Y)
{
    __shared__ __align__(16) float u_s[160];
    __shared__ __align__(16) float w_s[560];
    const int f = blockIdx.x;
    const int b = blockIdx.y;
    const int tid = threadIdx.x;
    const float* irow = IR + ((size_t)b * 1000 + f) * 158;
    for (int i = tid; i < 160; i += 128) {
        u_s[i] = (i < 158) ? irow[i] : 0.0f;
        w_s[i] = 0.0f;
        w_s[400 + i] = 0.0f;
    }
    for (int i = tid; i < 240; i += 128)
        w_s[160 + i] = audio[(size_t)b * 240000 + (size_t)f * 240 + i];
    __syncthreads();

    const int j0 = tid << 2;
    if (j0 >= 400) return;
    int base = 160 + j0 - 4;
    float4 Wlo = *(const float4*)&w_s[base];
    float4 Whi = *(const float4*)&w_s[base + 4];
    float a0 = 0.f, a1 = 0.f, a2 = 0.f, a3 = 0.f;
    #pragma unroll 4
    for (int t = 0; t < 156; t += 4) {
        float4 u4 = *(const float4*)&u_s[t];
        CONV_GROUP(u4)
        Whi = Wlo;
        base -= 4;
        Wlo = *(const float4*)&w_s[base];
    }
    {
        float4 u4 = *(const float4*)&u_s[156];
        CONV_GROUP(u4)
    }
    float4 r; r.x = a0; r.y = a1; r.z = a2; r.w = a3;
    *(float4*)&Y[((size_t)b * 1000 + f) * 400 + j0] = r;
}

// ---------------------------------------------------------------------------
// Overlap-add + 'same' slice + outputs (full range, single launch)
// ---------------------------------------------------------------------------
__global__ __launch_bounds__(256) void combine_kernel(
    const float* __restrict__ Yh, const float* __restrict__ Yn,
    float* __restrict__ sig, float* __restrict__ harm, float* __restrict__ noise)
{
    int t = blockIdx.x * 256 + threadIdx.x;
    if (t >= 240000) return;
    const int b = blockIdx.y;
    float hsum = 0.0f;
    const int fhi = (t + 509) / 240;
    #pragma unroll
    for (int q = 0; q < 6; q++) {
        int f = fhi - q;
        int j = t + 509 - 240 * f;
        if (f >= 0 && f < 1000 && j < 1261)
            hsum += Yh[((size_t)b * 1000 + f) * 1280 + j];
    }
    float nsum = 0.0f;
    const int ghi = (t + 77) / 240;
    #pragma unroll
    for (int q = 0; q < 2; q++) {
        int f = ghi - q;
        int j = t + 77 - 240 * f;
        if (f >= 0 && f < 1000 && j < 397)
            nsum += Yn[((size_t)b * 1000 + f) * 400 + j];
    }
    size_t o = (size_t)b * 240000 + t;
    harm[o]  = hsum;
    noise[o] = nsum;
    sig[o]   = hsum + nsum;
}

// ---------------------------------------------------------------------------
extern "C" void kernel_launch(void* const* d_in, const int* in_sizes, int n_in,
                              void* d_out, int out_size, void* d_ws, size_t ws_size,
                              hipStream_t stream)
{
    (void)in_sizes; (void)n_in; (void)out_size; (void)ws_size;
    const float* mel    = (const float*)d_in[0];
    const float* iphase = (const float*)d_in[1];
    const float* W_in   = (const float*)d_in[2];
    const float* b_in   = (const float*)d_in[3];
    const float* W1     = (const float*)d_in[4];
    const float* b1     = (const float*)d_in[5];
    const float* W2     = (const float*)d_in[6];
    const float* b2     = (const float*)d_in[7];
    const float* W_out  = (const float*)d_in[8];
    const float* b_out  = (const float*)d_in[9];
    float* ws = (float*)d_ws;

    // workspace layout (float offsets), peak 32,338,560 floats = 129.4 MB
    __hip_bfloat16* Chb = (__hip_bfloat16*)(ws + 0);        // [1024][512] bf16
    float*  Cn      = ws + 262144;                          // 12,640
    __hip_bfloat16* SPb = (__hip_bfloat16*)(ws + 274784);   // [8000][512] bf16
    float*  NP      = ws + 2322784;                         // 640,000
    float*  f0w     = ws + 3440640;                         // 8,000
    double* base    = (double*)(ws + 3448640);              // 8,000 dbl
    float*  saw     = ws + 3472640;                         // 1,920,000
    float*  nz      = ws + 5392640;                         // 1,920,000
    float*  BA      = ws + 7312640;                         // 2,048,000 (h1,h3)
    float*  BB      = ws + 9360640;                         // 2,048,000 (h2)
    __hip_bfloat16* BAb = (__hip_bfloat16*)(ws + 11408640); // [8000][256] bf16
    __hip_bfloat16* WTb = (__hip_bfloat16*)(ws + 12432640); // [640][256] bf16
    float*  O       = ws + 12514560;                        // [8000][640]
    float*  IRh     = ws + 7312640;                         // [8000][1024] (aliases BA..O, dead then)
    float*  IRn     = ws + 17634560;                        // 1,264,000
    float*  YhF     = ws + 18898560;                        // [8][1000][1280] = 10,240,000
    float*  YnF     = ws + 29138560;                        // [8][1000][400]  =  3,200,000

    float* out       = (float*)d_out;
    float* sig_out   = out;
    float* f0_out    = out + 1920000;
    float* fph_out   = out + 1928000;
    float* harm_out  = out + 1928008;
    float* noise_out = out + 3848008;

    basis_h_bf16_t<<<1024, 256, 0, stream>>>(Chb);
    basis_kernel<80, 158><<<80, 256, 0, stream>>>(Cn);

    // MLP hidden layers in fp32 (f0-precision path); 3rd layer mirrors bf16
    gemm_kernel<0><<<dim3(125, 4), 256, 0, stream>>>(mel, W_in, b_in, nullptr, BA, nullptr, 8000, 256, 80);
    gemm_kernel<1><<<dim3(125, 4), 256, 0, stream>>>(BA,  W1,   b1,   BA,      BB, nullptr, 8000, 256, 256);
    gemm_kernel<1><<<dim3(125, 4), 256, 0, stream>>>(BB,  W2,   b2,   BB,      BA, BAb,     8000, 256, 256);

    // W_out: bf16 MFMA for SP/NP columns + exact fp32 GEMV (fused f0) for col 0
    convert_wout<<<640, 256, 0, stream>>>(W_out, WTb);
    mfma_gemm<256, 640><<<dim3(63, 5), 256, 0, stream>>>(
        (const unsigned short*)BAb, (const unsigned short*)WTb, O, 8000);
    f0_gemv<<<2000, 256, 0, stream>>>(BA, W_out, b_out, f0w, f0_out);

    transform2_kernel<<<(8000 * 592 + 255) / 256, 256, 0, stream>>>(O, b_out, SPb, NP);
    scan_par_kernel<<<8, 256, 0, stream>>>(f0w, iphase, base, fph_out);
    saw_noise_kernel<<<(1920000 + 255) / 256, 256, 0, stream>>>(f0w, base, iphase, saw, nz);

    // IR_h = SPb @ Chb^T  (bf16 MFMA, fp32 out, stride 1024)
    mfma_gemm<512, 1024><<<dim3(63, 8), 256, 0, stream>>>(
        (const unsigned short*)SPb, (const unsigned short*)Chb, IRh, 8000);
    // IR_n fp32
    gemm_kernel<2><<<dim3(125, 3), 256, 0, stream>>>(NP, Cn, nullptr, nullptr, IRn, nullptr, 8000, 158, 80);

    // per-frame conv + overlap-add (single pass, no chunking)
    frameconv_h<<<dim3(1000, 8), 320, 0, stream>>>(saw, IRh, YhF);
    frameconv_n<<<dim3(1000, 8), 128, 0, stream>>>(nz, IRn, YnF);
    combine_kernel<<<dim3(938, 8), 256, 0, stream>>>(YhF, YnF, sig_out, harm_out, noise_out);
}

// Round 9
// 301.258 us; speedup vs baseline: 1.3628x; 1.3628x over previous
//
#include <hip/hip_runtime.h>
#include <hip/hip_bf16.h>
#include <math.h>

#define TWO_PI_D 6.283185307179586476925286766559
#define TWO_PI_F 6.28318530718f

typedef short bf16x8 __attribute__((ext_vector_type(8)));
typedef float f32x4 __attribute__((ext_vector_type(4)));

// ---------------------------------------------------------------------------
// Harmonic basis, bf16, TRANSPOSED + padded: Ct[n][k], n<1024 (1022 valid), k<512
// ---------------------------------------------------------------------------
__global__ __launch_bounds__(256) void basis_h_bf16_t(__hip_bfloat16* __restrict__ Ct)
{
    const int n = blockIdx.x;            // 0..1023
    for (int k = threadIdx.x; k < 512; k += 256) {
        float v = 0.0f;
        if (n < 1022) {
            float hann = 0.5f * (1.0f - cosf(TWO_PI_F * (float)n / 1022.0f));
            float w = hann * (1.0f / 1022.0f);
            if (k == 0) v = w;
            else if (k == 511) v = (n & 1) ? w : -w;
            else {
                int m = (k * n) % 1022;
                float c = cosf(TWO_PI_F * (float)m / 1022.0f);
                v = 2.0f * w * ((k & 1) ? -c : c);
            }
        }
        Ct[(size_t)n * 512 + k] = __float2bfloat16(v);
    }
}

// noise basis, fp32: C[k][n], k<80, n<158
template<int NMAG, int NIR>
__global__ __launch_bounds__(256) void basis_kernel(float* __restrict__ C)
{
    const int k = blockIdx.x;
    for (int n = threadIdx.x; n < NIR; n += blockDim.x) {
        double hann = 0.5 * (1.0 - cos(TWO_PI_D * (double)n / (double)NIR));
        double w = hann / (double)NIR;
        double v;
        if (k == 0) v = w;
        else if (k == NMAG - 1) v = (n & 1) ? w : -w;
        else {
            long m = ((long)k * (long)n) % NIR;
            double c = cos(TWO_PI_D * (double)m / (double)NIR);
            v = 2.0 * w * ((k & 1) ? -c : c);
        }
        C[(size_t)k * NIR + n] = (float)v;
    }
}

// ---------------------------------------------------------------------------
// fp32 tiled GEMM 64x64x16 — precision path (MLP hidden layers + noise IR).
// ---------------------------------------------------------------------------
__device__ inline float gelu_f(float x) {
    float x3 = x * x * x;
    float t = tanhf(0.7978845608028654f * (x + 0.044715f * x3));
    return 0.5f * x * (1.0f + t);
}

template<int MODE>
__global__ __launch_bounds__(256) void gemm_kernel(
    const float* __restrict__ A, const float* __restrict__ Bm,
    const float* __restrict__ bias, const float* __restrict__ resid,
    float* __restrict__ C, __hip_bfloat16* __restrict__ Cb, int M, int N, int K)
{
    __shared__ float As[16][68];
    __shared__ float Bs[16][68];
    const int tid = threadIdx.x;
    const int tx = tid & 15, ty = tid >> 4;
    const int m0 = blockIdx.x * 64;
    const int n0 = blockIdx.y * 64;
    const int ar  = tid >> 2;
    const int ac4 = (tid & 3) << 2;
    const int bk  = tid >> 4;
    const int bn4 = (tid & 15) << 2;
    float acc[4][4] = {};
    for (int k0 = 0; k0 < K; k0 += 16) {
        float4 av = *(const float4*)(A + (size_t)(m0 + ar) * K + k0 + ac4);
        As[ac4 + 0][ar] = av.x;
        As[ac4 + 1][ar] = av.y;
        As[ac4 + 2][ar] = av.z;
        As[ac4 + 3][ar] = av.w;
        const float* Bp = Bm + (size_t)(k0 + bk) * N + n0 + bn4;
        #pragma unroll
        for (int i = 0; i < 4; i++)
            Bs[bk][bn4 + i] = (n0 + bn4 + i < N) ? Bp[i] : 0.0f;
        __syncthreads();
        #pragma unroll
        for (int kk = 0; kk < 16; kk++) {
            float4 a4 = *(const float4*)&As[kk][ty << 2];
            float4 b4 = *(const float4*)&Bs[kk][tx << 2];
            float a[4] = {a4.x, a4.y, a4.z, a4.w};
            float b[4] = {b4.x, b4.y, b4.z, b4.w};
            #pragma unroll
            for (int i = 0; i < 4; i++)
                #pragma unroll
                for (int j = 0; j < 4; j++)
                    acc[i][j] = fmaf(a[i], b[j], acc[i][j]);
        }
        __syncthreads();
    }
    #pragma unroll
    for (int i = 0; i < 4; i++) {
        int m = m0 + (ty << 2) + i;
        #pragma unroll
        for (int j = 0; j < 4; j++) {
            int n = n0 + (tx << 2) + j;
            if (n < N) {
                float v = acc[i][j];
                if (bias) v += bias[n];
                if (MODE == 0) v = tanhf(v);
                else if (MODE == 1) v = resid[(size_t)m * N + n] + gelu_f(v);
                C[(size_t)m * N + n] = v;
                if (MODE == 1 && Cb) Cb[(size_t)m * N + n] = __float2bfloat16(v);
            }
        }
    }
}

// ---------------------------------------------------------------------------
// bf16 MFMA GEMM: A [M][K] bf16, Bt [NPAD][K] bf16, C [M][NSTRIDE] fp32
// ---------------------------------------------------------------------------
template<int K, int NSTRIDE>
__global__ __launch_bounds__(256) void mfma_gemm(
    const unsigned short* __restrict__ A, const unsigned short* __restrict__ Bt,
    float* __restrict__ C, int M)
{
    __shared__ __align__(16) unsigned short As[128][72];
    __shared__ __align__(16) unsigned short Bs[128][72];
    const int tid = threadIdx.x;
    const int m0 = blockIdx.x * 128;
    const int n0 = blockIdx.y * 128;
    const int wid = tid >> 6;
    const int lane = tid & 63;
    const int wm = (wid >> 1) << 6;
    const int wn = (wid & 1) << 6;

    f32x4 acc[4][4];
    #pragma unroll
    for (int i = 0; i < 4; i++)
        #pragma unroll
        for (int j = 0; j < 4; j++)
            acc[i][j] = (f32x4){0.f, 0.f, 0.f, 0.f};

    for (int k0 = 0; k0 < K; k0 += 64) {
        #pragma unroll
        for (int s = 0; s < 4; s++) {
            int g = tid + (s << 8);
            int row = g >> 3;
            int kc = (g & 7) << 3;
            int ra = m0 + row; if (ra > M - 1) ra = M - 1;
            *(uint4*)&As[row][kc] = *(const uint4*)&A[(size_t)ra * K + k0 + kc];
            *(uint4*)&Bs[row][kc] = *(const uint4*)&Bt[(size_t)(n0 + row) * K + k0 + kc];
        }
        __syncthreads();
        #pragma unroll
        for (int kk = 0; kk < 64; kk += 32) {
            bf16x8 av[4], bv[4];
            const int koff = kk + ((lane >> 4) << 3);
            #pragma unroll
            for (int mt = 0; mt < 4; mt++)
                av[mt] = *(const bf16x8*)&As[wm + (mt << 4) + (lane & 15)][koff];
            #pragma unroll
            for (int nt = 0; nt < 4; nt++)
                bv[nt] = *(const bf16x8*)&Bs[wn + (nt << 4) + (lane & 15)][koff];
            #pragma unroll
            for (int mt = 0; mt < 4; mt++)
                #pragma unroll
                for (int nt = 0; nt < 4; nt++)
                    acc[mt][nt] = __builtin_amdgcn_mfma_f32_16x16x32_bf16(
                        av[mt], bv[nt], acc[mt][nt], 0, 0, 0);
        }
        __syncthreads();
    }
    const int cr0 = m0 + wm + ((lane >> 4) << 2);
    const int cc0 = n0 + wn + (lane & 15);
    #pragma unroll
    for (int mt = 0; mt < 4; mt++)
        #pragma unroll
        for (int nt = 0; nt < 4; nt++)
            #pragma unroll
            for (int j = 0; j < 4; j++) {
                int r = cr0 + (mt << 4) + j;
                if (r < M) C[(size_t)r * NSTRIDE + cc0 + (nt << 4)] = acc[mt][nt][j];
            }
}

// ---------------------------------------------------------------------------
__global__ __launch_bounds__(256) void convert_wout(
    const float* __restrict__ W, __hip_bfloat16* __restrict__ WTb)
{
    const int n = blockIdx.x;           // 0..639
    const int k = threadIdx.x;          // 0..255
    float v = (n < 593) ? W[(size_t)k * 593 + n] : 0.0f;
    WTb[(size_t)n * 256 + k] = __float2bfloat16(v);
}

// exact-fp32 f0 logit + fused precise f0 transform
__global__ __launch_bounds__(256) void f0_gemv(
    const float* __restrict__ h3, const float* __restrict__ Wout,
    const float* __restrict__ b_out, float* __restrict__ f0w, float* __restrict__ f0out)
{
    const int row = blockIdx.x * 4 + (threadIdx.x >> 6);
    const int lane = threadIdx.x & 63;
    const float* a = h3 + (size_t)row * 256;
    float s = 0.0f;
    #pragma unroll
    for (int q = 0; q < 4; q++) {
        int k = lane + (q << 6);
        s = fmaf(a[k], Wout[(size_t)k * 593], s);
    }
    #pragma unroll
    for (int off = 32; off; off >>= 1) s += __shfl_down(s, off, 64);
    if (lane == 0) {
        float lg = s + b_out[0];
        float sg = 1.0f / (1.0f + expf(-lg));
        float f0 = 80.0f * powf(12.5f, sg);
        if (f0 < 80.0f) f0 = 0.0f;
        f0w[row] = f0;
        f0out[row] = f0;
    }
}

// ---------------------------------------------------------------------------
// SP/NP from O[8000][640] cols 1..592 (+bias), fast-math exp_sigmoid
// ---------------------------------------------------------------------------
__global__ __launch_bounds__(256) void transform2_kernel(
    const float* __restrict__ O, const float* __restrict__ b_out,
    __hip_bfloat16* __restrict__ SPb, float* __restrict__ NP)
{
    int idx = blockIdx.x * 256 + threadIdx.x;
    if (idx >= 8000 * 592) return;
    int row = idx / 592;
    int c = idx - row * 592 + 1;
    float v = O[(size_t)row * 640 + c] + b_out[c];
    float s = 1.0f / (1.0f + __expf(-v));
    float p = 2.0f * __powf(s, 2.3025851f) + 1e-7f;
    if (c < 513) SPb[(size_t)row * 512 + (c - 1)] = __float2bfloat16(p);
    else         NP[(size_t)row * 80 + (c - 513)] = p;
}

// ---------------------------------------------------------------------------
// Parallel fp64 frame-level pitch scan
// ---------------------------------------------------------------------------
__device__ inline double shfl_up_d(double x, int off) {
    long long l = __double_as_longlong(x);
    int lo = (int)(l & 0xffffffffLL);
    int hi = (int)(l >> 32);
    lo = __shfl_up(lo, off, 64);
    hi = __shfl_up(hi, off, 64);
    return __longlong_as_double(((long long)hi << 32) | (unsigned int)lo);
}

__global__ __launch_bounds__(256) void scan_par_kernel(
    const float* __restrict__ f0w, const float* __restrict__ iphase,
    double* __restrict__ base, float* __restrict__ fph)
{
    __shared__ double wsum[4];
    const int b = blockIdx.x;
    const int tid = threadIdx.x;
    const int lane = tid & 63;
    const float* f0 = f0w + b * 1000;
    double s[4];
    double loc = 0.0;
    #pragma unroll
    for (int q = 0; q < 4; q++) {
        int f = tid * 4 + q;
        s[q] = loc;
        if (f < 1000) {
            double c  = (double)f0[f];
            double nx = (double)f0[(f < 999) ? (f + 1) : 999];
            loc += 120.5 * c + 119.5 * nx;
        }
    }
    double v = loc;
    #pragma unroll
    for (int off = 1; off < 64; off <<= 1) {
        double o = shfl_up_d(v, off);
        if (lane >= off) v += o;
    }
    if (lane == 63) wsum[tid >> 6] = v;
    __syncthreads();
    double wpre = 0.0;
    const int w = tid >> 6;
    for (int i = 0; i < w; i++) wpre += wsum[i];
    const double excl = wpre + v - loc;
    #pragma unroll
    for (int q = 0; q < 4; q++) {
        int f = tid * 4 + q;
        if (f < 1000) base[b * 1000 + f] = excl + s[q];
    }
    if (tid == 255) {
        double total = excl + loc;
        double u  = total * (1.0 / 24000.0);
        double ph = TWO_PI_D * u + (double)iphase[b];
        fph[b] = (float)fmod(ph, TWO_PI_D);
    }
}

// ---------------------------------------------------------------------------
// Sawtooth (fp64 phase) + threefry2x32 noise (bit-exact)
// ---------------------------------------------------------------------------
__device__ inline unsigned rotl32(unsigned x, int d) { return (x << d) | (x >> (32 - d)); }

__global__ __launch_bounds__(256) void saw_noise_kernel(
    const float* __restrict__ f0w, const double* __restrict__ base,
    const float* __restrict__ iphase, float* __restrict__ saw, float* __restrict__ nz)
{
    int idx = blockIdx.x * 256 + threadIdx.x;
    if (idx >= 8 * 240000) return;
    int b = idx / 240000;
    int t = idx - b * 240000;
    int f = t / 240;
    int r = t - f * 240;
    double c  = (double)f0w[b * 1000 + f];
    double nx = (double)f0w[b * 1000 + ((f < 999) ? (f + 1) : 999)];
    double rr = (double)r;
    double Bc = rr * (rr + 1.0) * (1.0 / 480.0);
    double Ac = (rr + 1.0) - Bc;
    double cum = base[b * 1000 + f] + Ac * c + Bc * nx;
    double u  = cum * (1.0 / 24000.0) + (double)iphase[b] * (1.0 / TWO_PI_D);
    double fr = u - floor(u);
    saw[idx] = (float)(2.0 * fr - 1.0);

    const unsigned n2 = 960000u;
    unsigned mi = (unsigned)idx;
    unsigned i0 = (mi < n2) ? mi : (mi - n2);
    unsigned x0 = i0, x1 = i0 + n2;
    const unsigned ks0 = 0u, ks1 = 123u, ks2 = 0x1BD11BDAu ^ 0u ^ 123u;
    x0 += ks0; x1 += ks1;
#define TF_R(rot) { x0 += x1; x1 = rotl32(x1, rot); x1 ^= x0; }
    TF_R(13) TF_R(15) TF_R(26) TF_R(6)
    x0 += ks1; x1 += ks2 + 1u;
    TF_R(17) TF_R(29) TF_R(16) TF_R(24)
    x0 += ks2; x1 += ks0 + 2u;
    TF_R(13) TF_R(15) TF_R(26) TF_R(6)
    x0 += ks0; x1 += ks1 + 3u;
    TF_R(17) TF_R(29) TF_R(16) TF_R(24)
    x0 += ks1; x1 += ks2 + 4u;
    TF_R(13) TF_R(15) TF_R(26) TF_R(6)
    x0 += ks2; x1 += ks0 + 5u;
#undef TF_R
    unsigned bits = (mi < n2) ? x0 : x1;
    float uf = __uint_as_float((bits >> 9) | 0x3f800000u) - 1.0f;
    nz[idx] = uf * 2.0f - 1.0f;
}

// ---------------------------------------------------------------------------
// Per-frame conv, harmonic. One WAVE per frame, 4 frames/block (256 thr).
// Lane owns 20 outputs (64*20=1280). Per-lane w stride = 5 chunks (odd) ->
// 8 consecutive lanes tile all 32 banks exactly once: conflict-free floor.
// u-reads are wave-uniform broadcasts. Rolling 6-chunk circular register
// window, period-6 full unroll (static slots, no register shifts).
// ---------------------------------------------------------------------------
__global__ __launch_bounds__(256) void frameconv_h(
    const float* __restrict__ audio, const float* __restrict__ IR,
    float* __restrict__ Y)
{
    constexpr int WOFF = 244;            // left zero-pad words (chunk-aligned)
    constexpr int WSZ  = 1536;           // per-frame padded w words
    __shared__ float u_s[4][240];
    __shared__ __align__(16) float w_s[4][WSZ];
    const int fq  = blockIdx.x;          // frame quad 0..249
    const int b   = blockIdx.y;
    const int tid = threadIdx.x;
    const int wv  = tid >> 6;            // wave = frame within quad
    const int lane = tid & 63;

    // staging (coalesced; zero pads outside [0,1022))
    for (int i = tid; i < 4 * WSZ; i += 256) {
        int fr = i / WSZ, r = i - fr * WSZ;
        int d = r - WOFF;
        float v = 0.0f;
        if (d >= 0 && d < 1022)
            v = IR[((size_t)b * 1000 + fq * 4 + fr) * 1024 + d];
        w_s[fr][r] = v;
    }
    for (int i = tid; i < 4 * 240; i += 256) {
        int fr = i / 240, r = i - fr * 240;
        u_s[fr][r] = audio[(size_t)b * 240000 + (size_t)(fq * 4 + fr) * 240 + r];
    }
    __syncthreads();

    const float* wf = w_s[wv];
    const float* uf = u_s[wv];
    const int j0 = 20 * lane;
    float acc[20];
    #pragma unroll
    for (int q = 0; q < 20; q++) acc[q] = 0.0f;

    // window: 6 chunks covering padded words [wb(s), wb(s)+24), wb(s) = WOFF+j0-4-4s
    float C[24];
    const int wb0 = WOFF + j0 - 4;       // = 240 + 20*lane (>= 0, 16B-aligned)
    #pragma unroll
    for (int h = 0; h < 6; h++)
        *(float4*)&C[4 * h] = *(const float4*)&wf[wb0 + 4 * h];
    int ldw = wb0 - 4;                   // next incoming chunk word

    #pragma unroll 1
    for (int M = 0; M < 10; M++) {
        #pragma unroll
        for (int p = 0; p < 6; p++) {    // global step s = 6M+p, i0 = 4s
            const int i0 = 24 * M + 4 * p;
            float4 u4 = *(const float4*)&uf[i0];
            float uu[4] = {u4.x, u4.y, u4.z, u4.w};
            #pragma unroll
            for (int q = 0; q < 20; q++)
                #pragma unroll
                for (int k = 0; k < 4; k++) {
                    const int rel  = q - k + 4;              // 1..23
                    const int h    = rel >> 2;               // 0..5
                    const int slot = ((h - p) % 6 + 6) % 6;  // static
                    acc[q] = fmaf(uu[k], C[4 * slot + (rel & 3)], acc[q]);
                }
            const int lslot = ((-1 - p) % 6 + 6) % 6;        // 5,4,..,0
            *(float4*)&C[4 * lslot] = *(const float4*)&wf[ldw];
            ldw -= 4;
        }
    }

    float* yp = &Y[((size_t)b * 1000 + fq * 4 + wv) * 1280 + j0];
    #pragma unroll
    for (int cc = 0; cc < 5; cc++) {
        float4 r4 = {acc[4*cc], acc[4*cc+1], acc[4*cc+2], acc[4*cc+3]};
        *(float4*)&yp[4*cc] = r4;
    }
}

// ---------------------------------------------------------------------------
// Per-frame conv, noise: iterate IR, window over audio.
// ---------------------------------------------------------------------------
#define CONV_GROUP(u4) \
    a0 = fmaf(u4.x, Whi.x, a0); a1 = fmaf(u4.x, Whi.y, a1); a2 = fmaf(u4.x, Whi.z, a2); a3 = fmaf(u4.x, Whi.w, a3); \
    a0 = fmaf(u4.y, Wlo.w, a0); a1 = fmaf(u4.y, Whi.x, a1); a2 = fmaf(u4.y, Whi.y, a2); a3 = fmaf(u4.y, Whi.z, a3); \
    a0 = fmaf(u4.z, Wlo.z, a0); a1 = fmaf(u4.z, Wlo.w, a1); a2 = fmaf(u4.z, Whi.x, a2); a3 = fmaf(u4.z, Whi.y, a3); \
    a0 = fmaf(u4.w, Wlo.y, a0); a1 = fmaf(u4.w, Wlo.z, a1); a2 = fmaf(u4.w, Wlo.w, a2); a3 = fmaf(u4.w, Whi.x, a3);

__global__ __launch_bounds__(128) void frameconv_n(
    const float* __restrict__ audio, const float* __restrict__ IR,
    float* __restrict__ Y)
{
    __shared__ __align__(16) float u_s[160];
    __shared__ __align__(16) float w_s[560];
    const int f = blockIdx.x;
    const int b = blockIdx.y;
    const int tid = threadIdx.x;
    const float* irow = IR + ((size_t)b * 1000 + f) * 158;
    for (int i = tid; i < 160; i += 128) {
        u_s[i] = (i < 158) ? irow[i] : 0.0f;
        w_s[i] = 0.0f;
        w_s[400 + i] = 0.0f;
    }
    for (int i = tid; i < 240; i += 128)
        w_s[160 + i] = audio[(size_t)b * 240000 + (size_t)f * 240 + i];
    __syncthreads();

    const int j0 = tid << 2;
    if (j0 >= 400) return;
    int base = 160 + j0 - 4;
    float4 Wlo = *(const float4*)&w_s[base];
    float4 Whi = *(const float4*)&w_s[base + 4];
    float a0 = 0.f, a1 = 0.f, a2 = 0.f, a3 = 0.f;
    #pragma unroll 4
    for (int t = 0; t < 156; t += 4) {
        float4 u4 = *(const float4*)&u_s[t];
        CONV_GROUP(u4)
        Whi = Wlo;
        base -= 4;
        Wlo = *(const float4*)&w_s[base];
    }
    {
        float4 u4 = *(const float4*)&u_s[156];
        CONV_GROUP(u4)
    }
    float4 r; r.x = a0; r.y = a1; r.z = a2; r.w = a3;
    *(float4*)&Y[((size_t)b * 1000 + f) * 400 + j0] = r;
}

// ---------------------------------------------------------------------------
// Overlap-add + 'same' slice + outputs (full range, single launch)
// ---------------------------------------------------------------------------
__global__ __launch_bounds__(256) void combine_kernel(
    const float* __restrict__ Yh, const float* __restrict__ Yn,
    float* __restrict__ sig, float* __restrict__ harm, float* __restrict__ noise)
{
    int t = blockIdx.x * 256 + threadIdx.x;
    if (t >= 240000) return;
    const int b = blockIdx.y;
    float hsum = 0.0f;
    const int fhi = (t + 509) / 240;
    #pragma unroll
    for (int q = 0; q < 6; q++) {
        int f = fhi - q;
        int j = t + 509 - 240 * f;
        if (f >= 0 && f < 1000 && j < 1261)
            hsum += Yh[((size_t)b * 1000 + f) * 1280 + j];
    }
    float nsum = 0.0f;
    const int ghi = (t + 77) / 240;
    #pragma unroll
    for (int q = 0; q < 2; q++) {
        int f = ghi - q;
        int j = t + 77 - 240 * f;
        if (f >= 0 && f < 1000 && j < 397)
            nsum += Yn[((size_t)b * 1000 + f) * 400 + j];
    }
    size_t o = (size_t)b * 240000 + t;
    harm[o]  = hsum;
    noise[o] = nsum;
    sig[o]   = hsum + nsum;
}

// ---------------------------------------------------------------------------
extern "C" void kernel_launch(void* const* d_in, const int* in_sizes, int n_in,
                              void* d_out, int out_size, void* d_ws, size_t ws_size,
                              hipStream_t stream)
{
    (void)in_sizes; (void)n_in; (void)out_size; (void)ws_size;
    const float* mel    = (const float*)d_in[0];
    const float* iphase = (const float*)d_in[1];
    const float* W_in   = (const float*)d_in[2];
    const float* b_in   = (const float*)d_in[3];
    const float* W1     = (const float*)d_in[4];
    const float* b1     = (const float*)d_in[5];
    const float* W2     = (const float*)d_in[6];
    const float* b2     = (const float*)d_in[7];
    const float* W_out  = (const float*)d_in[8];
    const float* b_out  = (const float*)d_in[9];
    float* ws = (float*)d_ws;

    // workspace layout (float offsets), peak 32,338,560 floats = 129.4 MB
    __hip_bfloat16* Chb = (__hip_bfloat16*)(ws + 0);        // [1024][512] bf16
    float*  Cn      = ws + 262144;                          // 12,640
    __hip_bfloat16* SPb = (__hip_bfloat16*)(ws + 274784);   // [8000][512] bf16
    float*  NP      = ws + 2322784;                         // 640,000
    float*  f0w     = ws + 3440640;                         // 8,000
    double* base    = (double*)(ws + 3448640);              // 8,000 dbl
    float*  saw     = ws + 3472640;                         // 1,920,000
    float*  nz      = ws + 5392640;                         // 1,920,000
    float*  BA      = ws + 7312640;                         // 2,048,000 (h1,h3)
    float*  BB      = ws + 9360640;                         // 2,048,000 (h2)
    __hip_bfloat16* BAb = (__hip_bfloat16*)(ws + 11408640); // [8000][256] bf16
    __hip_bfloat16* WTb = (__hip_bfloat16*)(ws + 12432640); // [640][256] bf16
    float*  O       = ws + 12514560;                        // [8000][640]
    float*  IRh     = ws + 7312640;                         // [8000][1024] (aliases BA..O, dead then)
    float*  IRn     = ws + 17634560;                        // 1,264,000
    float*  YhF     = ws + 18898560;                        // [8][1000][1280] = 10,240,000
    float*  YnF     = ws + 29138560;                        // [8][1000][400]  =  3,200,000

    float* out       = (float*)d_out;
    float* sig_out   = out;
    float* f0_out    = out + 1920000;
    float* fph_out   = out + 1928000;
    float* harm_out  = out + 1928008;
    float* noise_out = out + 3848008;

    basis_h_bf16_t<<<1024, 256, 0, stream>>>(Chb);
    basis_kernel<80, 158><<<80, 256, 0, stream>>>(Cn);

    // MLP hidden layers in fp32 (f0-precision path); 3rd layer mirrors bf16
    gemm_kernel<0><<<dim3(125, 4), 256, 0, stream>>>(mel, W_in, b_in, nullptr, BA, nullptr, 8000, 256, 80);
    gemm_kernel<1><<<dim3(125, 4), 256, 0, stream>>>(BA,  W1,   b1,   BA,      BB, nullptr, 8000, 256, 256);
    gemm_kernel<1><<<dim3(125, 4), 256, 0, stream>>>(BB,  W2,   b2,   BB,      BA, BAb,     8000, 256, 256);

    // W_out: bf16 MFMA for SP/NP columns + exact fp32 GEMV (fused f0) for col 0
    convert_wout<<<640, 256, 0, stream>>>(W_out, WTb);
    mfma_gemm<256, 640><<<dim3(63, 5), 256, 0, stream>>>(
        (const unsigned short*)BAb, (const unsigned short*)WTb, O, 8000);
    f0_gemv<<<2000, 256, 0, stream>>>(BA, W_out, b_out, f0w, f0_out);

    transform2_kernel<<<(8000 * 592 + 255) / 256, 256, 0, stream>>>(O, b_out, SPb, NP);
    scan_par_kernel<<<8, 256, 0, stream>>>(f0w, iphase, base, fph_out);
    saw_noise_kernel<<<(1920000 + 255) / 256, 256, 0, stream>>>(f0w, base, iphase, saw, nz);

    // IR_h = SPb @ Chb^T  (bf16 MFMA, fp32 out, stride 1024)
    mfma_gemm<512, 1024><<<dim3(63, 8), 256, 0, stream>>>(
        (const unsigned short*)SPb, (const unsigned short*)Chb, IRh, 8000);
    // IR_n fp32
    gemm_kernel<2><<<dim3(125, 3), 256, 0, stream>>>(NP, Cn, nullptr, nullptr, IRn, nullptr, 8000, 158, 80);

    // per-frame conv + overlap-add (single pass, no chunking)
    frameconv_h<<<dim3(250, 8), 256, 0, stream>>>(saw, IRh, YhF);
    frameconv_n<<<dim3(1000, 8), 128, 0, stream>>>(nz, IRn, YnF);
    combine_kernel<<<dim3(938, 8), 256, 0, stream>>>(YhF, YnF, sig_out, harm_out, noise_out);
}